// Round 11
// baseline (365.176 us; speedup 1.0000x reference)
//
#include <hip/hip_runtime.h>
#include <cstdint>
#include <cstddef>

// ---------------------------------------------------------------------------
// GraphSAGE 3-layer forward.
//   layer: out = act( mean_gather(h @ W_l) + (h @ W_r + b) )   (linearity swap)
// R8: MFMA GEMM (B-stationary, LDS-free), bf16 h/p. R9: dst-sliced csr_fill.
// R10/R11: (a) nontemporal loads on all streaming reads -- src/dst in
//      hist/fill (R9 residual 30MB write-amp = L2 stream-thrash evicting esrc
//      lines), h in GEMM, r in aggregate; (b) r stored bf16 for layers 0/1
//      (self-path re-rounded to bf16 in h anyway; layer2 r stays f32);
//      (c) fused partial-scan into scan_write + single prep kernel.
// R11 fix: __builtin_nontemporal_load needs clang ext_vector_type pointers,
//      not HIP_vector_type (float4/float2 are classes) -> f32x4/f32x2.
// NOTE: harness delivers integer inputs as int32 -> edge_index is const int*.
// ---------------------------------------------------------------------------

#define HID 128
#define SCAN_CHUNK 1024
#define NSLICE 8
#define FILL_BLOCKS_PER_SLICE 104   // grid = 832 blocks, slice = blockIdx & 7

using short8 = __attribute__((ext_vector_type(8))) short;
using f32x4  = __attribute__((ext_vector_type(4))) float;
using f32x2  = __attribute__((ext_vector_type(2))) float;

// ---- bf16 helpers (manual, RNE) -------------------------------------------

__device__ __forceinline__ unsigned short f32_to_bf16(float f)
{
    union { float f; unsigned int i; } c; c.f = f;
    const unsigned int x = c.i;
    const unsigned int r = x + 0x7fffu + ((x >> 16) & 1u);
    return (unsigned short)(r >> 16);
}

__device__ __forceinline__ float bf16_hi_to_f32(unsigned int hi16_in_low)
{
    union { unsigned int i; float f; } c; c.i = hi16_in_low << 16;
    return c.f;
}

// ---- small utility --------------------------------------------------------

__global__ __launch_bounds__(256) void zero_i32_kernel(int* __restrict__ p, int n)
{
    int i = blockIdx.x * 256 + threadIdx.x;
    if (i < n) p[i] = 0;
}

// ---- CSR build ------------------------------------------------------------

__global__ __launch_bounds__(256) void deg_hist_kernel(
    const int* __restrict__ dst, int* __restrict__ deg, int E, int n)
{
    int e = blockIdx.x * 256 + threadIdx.x;
    if (e < E) {
        int d = __builtin_nontemporal_load(&dst[e]);
        if (d >= 0 && d < n) atomicAdd(&deg[d], 1);
    }
}

__global__ __launch_bounds__(256) void block_sum_kernel(
    const int* __restrict__ deg, int* __restrict__ partials, int n)
{
    __shared__ int red[256];
    const int base = blockIdx.x * SCAN_CHUNK;
    const int t = threadIdx.x;
    int s = 0;
#pragma unroll
    for (int j = 0; j < 4; ++j) {
        const int idx = base + t * 4 + j;
        s += (idx < n) ? deg[idx] : 0;
    }
    red[t] = s;
    __syncthreads();
    for (int off = 128; off > 0; off >>= 1) {
        if (t < off) red[t] += red[t + off];
        __syncthreads();
    }
    if (t == 0) partials[blockIdx.x] = red[0];
}

// scan_write with fused prefix-of-partials: each block reduces partials[0..blk)
// itself (<=256 values, one tree reduce) -- kills the scan_partials launch.
__global__ __launch_bounds__(256) void scan_write_kernel(
    const int* __restrict__ deg, const int* __restrict__ partials,
    int* __restrict__ offs, int* __restrict__ cursor, int n, int E)
{
    __shared__ int red[256];
    __shared__ int buf[256];
    const int base = blockIdx.x * SCAN_CHUNK;
    const int t = threadIdx.x;

    // block base = sum of partials[0 .. blockIdx.x)
    red[t] = (t < (int)blockIdx.x) ? partials[t] : 0;
    __syncthreads();
    for (int off = 128; off > 0; off >>= 1) {
        if (t < off) red[t] += red[t + off];
        __syncthreads();
    }
    const int blockBase = red[0];
    __syncthreads();

    int loc[4];
    int s = 0;
#pragma unroll
    for (int j = 0; j < 4; ++j) {
        const int idx = base + t * 4 + j;
        const int d = (idx < n) ? deg[idx] : 0;
        loc[j] = s;
        s += d;
    }
    buf[t] = s;
    __syncthreads();
    for (int off = 1; off < 256; off <<= 1) {
        const int u = (t >= off) ? buf[t - off] : 0;
        __syncthreads();
        buf[t] += u;
        __syncthreads();
    }
    const int tbase = blockBase + ((t == 0) ? 0 : buf[t - 1]);
#pragma unroll
    for (int j = 0; j < 4; ++j) {
        const int idx = base + t * 4 + j;
        if (idx < n) {
            const int o = tbase + loc[j];
            offs[idx] = o;
            cursor[idx] = o;
        }
    }
    if (blockIdx.x == 0 && t == 0) offs[n] = E;
}

// dst-sliced CSR fill (slice = blockIdx & 7 -> per-XCD esrc write locality);
// nt loads keep the src/dst streams from evicting esrc lines out of L2.
__global__ __launch_bounds__(256) void csr_fill_sliced_kernel(
    const int* __restrict__ src, const int* __restrict__ dst,
    int* __restrict__ cursor, int* __restrict__ esrc, int E, int n)
{
    const int slice = blockIdx.x & (NSLICE - 1);
    const int nps   = (n + NSLICE - 1) / NSLICE;
    const int lo    = slice * nps;
    const int hi    = min(lo + nps, n);
    const int stride = FILL_BLOCKS_PER_SLICE * 256;
    int e = (blockIdx.x >> 3) * 256 + threadIdx.x;
    for (; e < E; e += stride) {
        const int d = __builtin_nontemporal_load(&dst[e]);
        if (d >= lo && d < hi) {
            const int s = __builtin_nontemporal_load(&src[e]);
            if ((unsigned)s < (unsigned)n) {
                const int p = atomicAdd(&cursor[d], 1);
                esrc[p] = s;
            }
        }
    }
}

// ---- combined W^T prep for all 3 layers (bf16) ----------------------------
// wt0/wt1: [256][128] (Wl||Wr, dout=128); wt2: [128][128] (dout=64).

__global__ __launch_bounds__(256) void prep_wt_all_kernel(
    const float* __restrict__ wl0, const float* __restrict__ wr0,
    const float* __restrict__ wl1, const float* __restrict__ wr1,
    const float* __restrict__ wl2, const float* __restrict__ wr2,
    unsigned short* __restrict__ wt0, unsigned short* __restrict__ wt1,
    unsigned short* __restrict__ wt2)
{
    const int idx = blockIdx.x * 256 + threadIdx.x;
    const int per128 = 2 * HID * HID;         // 32768
    if (idx < per128) {
        const int k = idx & (HID - 1), c = idx >> 7;
        const float v = (c < HID) ? wl0[(size_t)k * HID + c] : wr0[(size_t)k * HID + (c - HID)];
        wt0[idx] = f32_to_bf16(v);
    } else if (idx < 2 * per128) {
        const int j = idx - per128;
        const int k = j & (HID - 1), c = j >> 7;
        const float v = (c < HID) ? wl1[(size_t)k * HID + c] : wr1[(size_t)k * HID + (c - HID)];
        wt1[j] = f32_to_bf16(v);
    } else {
        const int j = idx - 2 * per128;
        if (j < 2 * 64 * HID) {
            const int k = j & (HID - 1), c = j >> 7;
            const float v = (c < 64) ? wl2[(size_t)k * 64 + c] : wr2[(size_t)k * 64 + (c - 64)];
            wt2[j] = f32_to_bf16(v);
        }
    }
}

// ---- MFMA dual GEMM: p = bf16(h@Wl), r = h@Wr + b -------------------------
// 256 thr = 4 waves; wave owns 64 cols; B-frags resident in registers;
// grid-stride over 16-row slabs; no LDS, no barriers. R_BF16: r stored bf16.

template <int DOUT, bool IN_F32, bool R_BF16>
__global__ __launch_bounds__(256) void sage_mfma_gemm(
    const void* __restrict__ hin,                 // [n][128] f32 or bf16
    const unsigned short* __restrict__ wtc,       // [2*DOUT][128] bf16
    const float* __restrict__ bias,
    unsigned short* __restrict__ p, void* __restrict__ r, int n)
{
    constexpr int TOTC = 2 * DOUT;
    constexpr int CPW  = TOTC / 64;   // col-tiles per wave: 4 (DOUT=128) or 2

    const int tx   = threadIdx.x;
    const int wv   = tx >> 6;
    const int lane = tx & 63;
    const int quad = lane >> 4;
    const int l15  = lane & 15;

    short8 B[CPW][4];
#pragma unroll
    for (int t = 0; t < CPW; ++t) {
        const int c = (wv * CPW + t) * 16 + l15;
#pragma unroll
        for (int q = 0; q < 4; ++q)
            B[t][q] = *(const short8*)(wtc + (size_t)c * HID + q * 32 + quad * 8);
    }

    const int slabs = (n + 15) >> 4;
    for (int slab = blockIdx.x; slab < slabs; slab += gridDim.x) {
        const int r0 = slab * 16;
        const int rr = min(r0 + l15, n - 1);

        short8 A[4];
        if (IN_F32) {
            const float* hf = (const float*)hin;
#pragma unroll
            for (int q = 0; q < 4; ++q) {
                const f32x4* base = (const f32x4*)(hf + (size_t)rr * HID + q * 32 + quad * 8);
                const f32x4 f0 = __builtin_nontemporal_load(base);
                const f32x4 f1 = __builtin_nontemporal_load(base + 1);
                short8 a;
                a[0] = (short)f32_to_bf16(f0.x); a[1] = (short)f32_to_bf16(f0.y);
                a[2] = (short)f32_to_bf16(f0.z); a[3] = (short)f32_to_bf16(f0.w);
                a[4] = (short)f32_to_bf16(f1.x); a[5] = (short)f32_to_bf16(f1.y);
                a[6] = (short)f32_to_bf16(f1.z); a[7] = (short)f32_to_bf16(f1.w);
                A[q] = a;
            }
        } else {
            const unsigned short* hb = (const unsigned short*)hin;
#pragma unroll
            for (int q = 0; q < 4; ++q)
                A[q] = __builtin_nontemporal_load(
                    (const short8*)(hb + (size_t)rr * HID + q * 32 + quad * 8));
        }

        f32x4 acc[CPW];
#pragma unroll
        for (int t = 0; t < CPW; ++t) acc[t] = (f32x4){0.f, 0.f, 0.f, 0.f};
#pragma unroll
        for (int q = 0; q < 4; ++q)
#pragma unroll
            for (int t = 0; t < CPW; ++t)
                acc[t] = __builtin_amdgcn_mfma_f32_16x16x32_bf16(A[q], B[t][q], acc[t], 0, 0, 0);

        // epilogue: C/D layout col=l15, row=quad*4+i
#pragma unroll
        for (int t = 0; t < CPW; ++t) {
            const int c0  = (wv * CPW + t) * 16;
            const int col = c0 + l15;
            if (c0 < DOUT) {
#pragma unroll
                for (int i = 0; i < 4; ++i) {
                    const int row = r0 + quad * 4 + i;
                    if (row < n) p[(size_t)row * DOUT + col] = f32_to_bf16(acc[t][i]);
                }
            } else {
                const float bv = bias[col - DOUT];
#pragma unroll
                for (int i = 0; i < 4; ++i) {
                    const int row = r0 + quad * 4 + i;
                    if (row < n) {
                        const float v = acc[t][i] + bv;
                        if (R_BF16)
                            ((unsigned short*)r)[(size_t)row * DOUT + (col - DOUT)] = f32_to_bf16(v);
                        else
                            ((float*)r)[(size_t)row * DOUT + (col - DOUT)] = v;
                    }
                }
            }
        }
    }
}

// ---- Post-aggregation: out = act( mean(p_bf16[nbrs]) + r ) ----------------
// One wave per dst node; predicated x8 unroll (8 gathers in flight).
// R_BF16: r is bf16; OUTBF16: write h as packed bf16.

template <int DOUT, bool RELU, bool OUTBF16, bool R_BF16>
__global__ __launch_bounds__(256) void sage_post_aggregate(
    const unsigned short* __restrict__ p, const void* __restrict__ r,
    const int* __restrict__ offs, const int* __restrict__ esrc,
    void* __restrict__ out, int n)
{
    const int wid  = threadIdx.x >> 6;
    const int lane = threadIdx.x & 63;
    const int node = blockIdx.x * 4 + wid;
    if (node >= n) return;
    const int beg = offs[node];
    const int end = offs[node + 1];
    const float inv = 1.0f / fmaxf((float)(end - beg), 1.0f);

    if constexpr (DOUT == 128) {
        float ax[8], ay[8];
#pragma unroll
        for (int j = 0; j < 8; ++j) { ax[j] = 0.f; ay[j] = 0.f; }
        for (int e = beg; e < end; e += 8) {
#pragma unroll
            for (int j = 0; j < 8; ++j) {
                const int idx = e + j;
                const int ee  = min(idx, end - 1);
                const float w = (idx < end) ? 1.0f : 0.0f;
                const int s   = esrc[ee];
                const unsigned int v = *(const unsigned int*)(&p[(size_t)s * DOUT + lane * 2]);
                ax[j] = fmaf(w, bf16_hi_to_f32(v & 0xffffu), ax[j]);
                ay[j] = fmaf(w, bf16_hi_to_f32(v >> 16), ay[j]);
            }
        }
        float sx = ((ax[0] + ax[1]) + (ax[2] + ax[3])) + ((ax[4] + ax[5]) + (ax[6] + ax[7]));
        float sy = ((ay[0] + ay[1]) + (ay[2] + ay[3])) + ((ay[4] + ay[5]) + (ay[6] + ay[7]));
        float rx, ry;
        if (R_BF16) {
            const unsigned int rv = __builtin_nontemporal_load(
                (const unsigned int*)r + (size_t)node * (DOUT / 2) + lane);
            rx = bf16_hi_to_f32(rv & 0xffffu);
            ry = bf16_hi_to_f32(rv >> 16);
        } else {
            const f32x2 rv = __builtin_nontemporal_load(
                (const f32x2*)((const float*)r + (size_t)node * DOUT) + lane);
            rx = rv.x; ry = rv.y;
        }
        float ox = sx * inv + rx;
        float oy = sy * inv + ry;
        if (RELU) { ox = fmaxf(ox, 0.f); oy = fmaxf(oy, 0.f); }
        if (OUTBF16) {
            const unsigned int pk = ((unsigned int)f32_to_bf16(oy) << 16) | (unsigned int)f32_to_bf16(ox);
            ((unsigned int*)out)[(size_t)node * (DOUT / 2) + lane] = pk;
        } else {
            f32x2 o; o.x = ox; o.y = oy;
            *((f32x2*)((float*)out + (size_t)node * DOUT) + lane) = o;
        }
    } else {
        float a[8];
#pragma unroll
        for (int j = 0; j < 8; ++j) a[j] = 0.f;
        for (int e = beg; e < end; e += 8) {
#pragma unroll
            for (int j = 0; j < 8; ++j) {
                const int idx = e + j;
                const int ee  = min(idx, end - 1);
                const float w = (idx < end) ? 1.0f : 0.0f;
                const int s   = esrc[ee];
                const unsigned short u = p[(size_t)s * DOUT + lane];
                a[j] = fmaf(w, bf16_hi_to_f32((unsigned int)u), a[j]);
            }
        }
        float sa = ((a[0] + a[1]) + (a[2] + a[3])) + ((a[4] + a[5]) + (a[6] + a[7]));
        float rv;
        if (R_BF16) {
            const unsigned short u = __builtin_nontemporal_load(
                (const unsigned short*)r + (size_t)node * DOUT + lane);
            rv = bf16_hi_to_f32((unsigned int)u);
        } else {
            rv = __builtin_nontemporal_load((const float*)r + (size_t)node * DOUT + lane);
        }
        float o = sa * inv + rv;
        if (RELU) o = fmaxf(o, 0.f);
        __builtin_nontemporal_store(o, (float*)out + (size_t)node * DOUT + lane);
    }
}

// ---------------------------------------------------------------------------

static inline size_t align_up(size_t v, size_t a) { return (v + a - 1) & ~(a - 1); }

extern "C" void kernel_launch(void* const* d_in, const int* in_sizes, int n_in,
                              void* d_out, int out_size, void* d_ws, size_t ws_size,
                              hipStream_t stream)
{
    const float* x   = (const float*)d_in[0];
    const int*   ei  = (const int*)d_in[1];      // int32! (harness converts int64)
    const float* wl0 = (const float*)d_in[2];
    const float* b0  = (const float*)d_in[3];
    const float* wr0 = (const float*)d_in[4];
    const float* wl1 = (const float*)d_in[5];
    const float* b1  = (const float*)d_in[6];
    const float* wr1 = (const float*)d_in[7];
    const float* wl2 = (const float*)d_in[8];
    const float* b2  = (const float*)d_in[9];
    const float* wr2 = (const float*)d_in[10];
    float*       out = (float*)d_out;

    const int N = in_sizes[0] / HID;   // 50000
    const int E = in_sizes[1] / 2;     // 800000
    const int* src = ei;
    const int* dst = ei + E;

    // Workspace carve-up (~42 MB)
    char*  ws  = (char*)d_ws;
    size_t off = 0;
    int* offs     = (int*)(ws + off); off = align_up(off + (size_t)(N + 1) * 4, 256);
    int* cursor   = (int*)(ws + off); off = align_up(off + (size_t)N * 4, 256);
    int* deg      = (int*)(ws + off); off = align_up(off + (size_t)N * 4, 256);
    int* partials = (int*)(ws + off); off = align_up(off + 256 * 4, 256);
    int* esrc     = (int*)(ws + off); off = align_up(off + (size_t)E * 4, 256);
    unsigned short* pbuf = (unsigned short*)(ws + off); off = align_up(off + (size_t)N * HID * 2, 256);
    unsigned short* rb16 = (unsigned short*)(ws + off); off = align_up(off + (size_t)N * HID * 2, 256);
    float* rbf32  = (float*)(ws + off); off = align_up(off + (size_t)N * HID * 4, 256);
    unsigned short* hbf = (unsigned short*)(ws + off); off = align_up(off + (size_t)N * HID * 2, 256);
    unsigned short* wt0 = (unsigned short*)(ws + off); off = align_up(off + (size_t)2 * HID * HID * 2, 256);
    unsigned short* wt1 = (unsigned short*)(ws + off); off = align_up(off + (size_t)2 * HID * HID * 2, 256);
    unsigned short* wt2 = (unsigned short*)(ws + off); off = align_up(off + (size_t)HID * HID * 2, 256);
    (void)ws_size; (void)n_in; (void)out_size;

    const int nScanBlk = (N + SCAN_CHUNK - 1) / SCAN_CHUNK;   // 49

    // --- CSR build (reused by all 3 layers) ---
    zero_i32_kernel<<<(N + 255) / 256, 256, 0, stream>>>(deg, N);
    deg_hist_kernel<<<(E + 255) / 256, 256, 0, stream>>>(dst, deg, E, N);
    block_sum_kernel<<<nScanBlk, 256, 0, stream>>>(deg, partials, N);
    scan_write_kernel<<<nScanBlk, 256, 0, stream>>>(deg, partials, offs, cursor, N, E);
    csr_fill_sliced_kernel<<<NSLICE * FILL_BLOCKS_PER_SLICE, 256, 0, stream>>>(
        src, dst, cursor, esrc, E, N);

    // --- W^T prep (all 3 layers, one launch) ---
    prep_wt_all_kernel<<<(2 * (2 * HID * HID) + 2 * 64 * HID + 255) / 256, 256, 0, stream>>>(
        wl0, wr0, wl1, wr1, wl2, wr2, wt0, wt1, wt2);

    const int aggGrid  = (N + 3) / 4;
    const int gemmGrid = 1024;   // grid-stride over 3125 slabs

    // Layer 0: x (f32) -> p/r(bf16) -> hbf (bf16, ReLU)
    sage_mfma_gemm<128, true, true><<<gemmGrid, 256, 0, stream>>>(x, wt0, b0, pbuf, rb16, N);
    sage_post_aggregate<128, true, true, true><<<aggGrid, 256, 0, stream>>>(pbuf, rb16, offs, esrc, hbf, N);

    // Layer 1: hbf -> p/r(bf16) -> hbf (bf16, ReLU)
    sage_mfma_gemm<128, false, true><<<gemmGrid, 256, 0, stream>>>(hbf, wt1, b1, pbuf, rb16, N);
    sage_post_aggregate<128, true, true, true><<<aggGrid, 256, 0, stream>>>(pbuf, rb16, offs, esrc, hbf, N);

    // Layer 2: hbf -> p(bf16)/r(f32) -> out (f32, no ReLU)
    sage_mfma_gemm<64, false, false><<<gemmGrid, 256, 0, stream>>>(hbf, wt2, b2, pbuf, rbf32, N);
    sage_post_aggregate<64, false, false, false><<<aggGrid, 256, 0, stream>>>(pbuf, rbf32, offs, esrc, out, N);
}

// Round 13
// 335.867 us; speedup vs baseline: 1.0873x; 1.0873x over previous
//
#include <hip/hip_runtime.h>
#include <cstdint>
#include <cstddef>

// ---------------------------------------------------------------------------
// GraphSAGE 3-layer forward.
//   layer: out = act( mean_gather(h @ W_l) + (h @ W_r + b) )   (linearity swap)
// R8: MFMA GEMM (B-stationary, LDS-free), bf16 h/p. R9: dst-sliced csr_fill.
// R11: nt loads REGRESSED (lost L2 hits; fill write-amp unchanged -> it's
//      cross-XCD partial-line bounce, not stream thrash). R12: cooperative
//      mega-kernel launch failed (grid > co-resident capacity; unified
//      VGPR/AGPR file pushed blocks/CU below assumed 4).
// R13: R11 minus ALL nontemporal builtins -- keep r-bf16 for layers 0/1 and
//      fused scan + merged W^T prep; plain cached loads everywhere.
// NOTE: harness delivers integer inputs as int32 -> edge_index is const int*.
// ---------------------------------------------------------------------------

#define HID 128
#define SCAN_CHUNK 1024
#define NSLICE 8
#define FILL_BLOCKS_PER_SLICE 104   // grid = 832 blocks, slice = blockIdx & 7

using short8 = __attribute__((ext_vector_type(8))) short;
using f32x4  = __attribute__((ext_vector_type(4))) float;

// ---- bf16 helpers (manual, RNE) -------------------------------------------

__device__ __forceinline__ unsigned short f32_to_bf16(float f)
{
    union { float f; unsigned int i; } c; c.f = f;
    const unsigned int x = c.i;
    const unsigned int r = x + 0x7fffu + ((x >> 16) & 1u);
    return (unsigned short)(r >> 16);
}

__device__ __forceinline__ float bf16_hi_to_f32(unsigned int hi16_in_low)
{
    union { unsigned int i; float f; } c; c.i = hi16_in_low << 16;
    return c.f;
}

// ---- small utility --------------------------------------------------------

__global__ __launch_bounds__(256) void zero_i32_kernel(int* __restrict__ p, int n)
{
    int i = blockIdx.x * 256 + threadIdx.x;
    if (i < n) p[i] = 0;
}

// ---- CSR build ------------------------------------------------------------

__global__ __launch_bounds__(256) void deg_hist_kernel(
    const int* __restrict__ dst, int* __restrict__ deg, int E, int n)
{
    int e = blockIdx.x * 256 + threadIdx.x;
    if (e < E) {
        int d = dst[e];
        if (d >= 0 && d < n) atomicAdd(&deg[d], 1);
    }
}

__global__ __launch_bounds__(256) void block_sum_kernel(
    const int* __restrict__ deg, int* __restrict__ partials, int n)
{
    __shared__ int red[256];
    const int base = blockIdx.x * SCAN_CHUNK;
    const int t = threadIdx.x;
    int s = 0;
#pragma unroll
    for (int j = 0; j < 4; ++j) {
        const int idx = base + t * 4 + j;
        s += (idx < n) ? deg[idx] : 0;
    }
    red[t] = s;
    __syncthreads();
    for (int off = 128; off > 0; off >>= 1) {
        if (t < off) red[t] += red[t + off];
        __syncthreads();
    }
    if (t == 0) partials[blockIdx.x] = red[0];
}

// scan_write with fused prefix-of-partials: each block reduces partials[0..blk)
// itself (<=256 values, one tree reduce) -- kills the scan_partials launch.
__global__ __launch_bounds__(256) void scan_write_kernel(
    const int* __restrict__ deg, const int* __restrict__ partials,
    int* __restrict__ offs, int* __restrict__ cursor, int n, int E)
{
    __shared__ int red[256];
    __shared__ int buf[256];
    const int base = blockIdx.x * SCAN_CHUNK;
    const int t = threadIdx.x;

    // block base = sum of partials[0 .. blockIdx.x)
    red[t] = (t < (int)blockIdx.x) ? partials[t] : 0;
    __syncthreads();
    for (int off = 128; off > 0; off >>= 1) {
        if (t < off) red[t] += red[t + off];
        __syncthreads();
    }
    const int blockBase = red[0];
    __syncthreads();

    int loc[4];
    int s = 0;
#pragma unroll
    for (int j = 0; j < 4; ++j) {
        const int idx = base + t * 4 + j;
        const int d = (idx < n) ? deg[idx] : 0;
        loc[j] = s;
        s += d;
    }
    buf[t] = s;
    __syncthreads();
    for (int off = 1; off < 256; off <<= 1) {
        const int u = (t >= off) ? buf[t - off] : 0;
        __syncthreads();
        buf[t] += u;
        __syncthreads();
    }
    const int tbase = blockBase + ((t == 0) ? 0 : buf[t - 1]);
#pragma unroll
    for (int j = 0; j < 4; ++j) {
        const int idx = base + t * 4 + j;
        if (idx < n) {
            const int o = tbase + loc[j];
            offs[idx] = o;
            cursor[idx] = o;
        }
    }
    if (blockIdx.x == 0 && t == 0) offs[n] = E;
}

// dst-sliced CSR fill (slice = blockIdx & 7 -> per-XCD esrc write locality).
__global__ __launch_bounds__(256) void csr_fill_sliced_kernel(
    const int* __restrict__ src, const int* __restrict__ dst,
    int* __restrict__ cursor, int* __restrict__ esrc, int E, int n)
{
    const int slice = blockIdx.x & (NSLICE - 1);
    const int nps   = (n + NSLICE - 1) / NSLICE;
    const int lo    = slice * nps;
    const int hi    = min(lo + nps, n);
    const int stride = FILL_BLOCKS_PER_SLICE * 256;
    int e = (blockIdx.x >> 3) * 256 + threadIdx.x;
    for (; e < E; e += stride) {
        const int d = dst[e];
        if (d >= lo && d < hi) {
            const int s = src[e];
            if ((unsigned)s < (unsigned)n) {
                const int p = atomicAdd(&cursor[d], 1);
                esrc[p] = s;
            }
        }
    }
}

// ---- combined W^T prep for all 3 layers (bf16) ----------------------------
// wt0/wt1: [256][128] (Wl||Wr, dout=128); wt2: [128][128] (dout=64).

__global__ __launch_bounds__(256) void prep_wt_all_kernel(
    const float* __restrict__ wl0, const float* __restrict__ wr0,
    const float* __restrict__ wl1, const float* __restrict__ wr1,
    const float* __restrict__ wl2, const float* __restrict__ wr2,
    unsigned short* __restrict__ wt0, unsigned short* __restrict__ wt1,
    unsigned short* __restrict__ wt2)
{
    const int idx = blockIdx.x * 256 + threadIdx.x;
    const int per128 = 2 * HID * HID;         // 32768
    if (idx < per128) {
        const int k = idx & (HID - 1), c = idx >> 7;
        const float v = (c < HID) ? wl0[(size_t)k * HID + c] : wr0[(size_t)k * HID + (c - HID)];
        wt0[idx] = f32_to_bf16(v);
    } else if (idx < 2 * per128) {
        const int j = idx - per128;
        const int k = j & (HID - 1), c = j >> 7;
        const float v = (c < HID) ? wl1[(size_t)k * HID + c] : wr1[(size_t)k * HID + (c - HID)];
        wt1[j] = f32_to_bf16(v);
    } else {
        const int j = idx - 2 * per128;
        if (j < 2 * 64 * HID) {
            const int k = j & (HID - 1), c = j >> 7;
            const float v = (c < 64) ? wl2[(size_t)k * 64 + c] : wr2[(size_t)k * 64 + (c - 64)];
            wt2[j] = f32_to_bf16(v);
        }
    }
}

// ---- MFMA dual GEMM: p = bf16(h@Wl), r = h@Wr + b -------------------------
// 256 thr = 4 waves; wave owns 64 cols; B-frags resident in registers;
// grid-stride over 16-row slabs; no LDS, no barriers. R_BF16: r stored bf16.

template <int DOUT, bool IN_F32, bool R_BF16>
__global__ __launch_bounds__(256) void sage_mfma_gemm(
    const void* __restrict__ hin,                 // [n][128] f32 or bf16
    const unsigned short* __restrict__ wtc,       // [2*DOUT][128] bf16
    const float* __restrict__ bias,
    unsigned short* __restrict__ p, void* __restrict__ r, int n)
{
    constexpr int TOTC = 2 * DOUT;
    constexpr int CPW  = TOTC / 64;   // col-tiles per wave: 4 (DOUT=128) or 2

    const int tx   = threadIdx.x;
    const int wv   = tx >> 6;
    const int lane = tx & 63;
    const int quad = lane >> 4;
    const int l15  = lane & 15;

    short8 B[CPW][4];
#pragma unroll
    for (int t = 0; t < CPW; ++t) {
        const int c = (wv * CPW + t) * 16 + l15;
#pragma unroll
        for (int q = 0; q < 4; ++q)
            B[t][q] = *(const short8*)(wtc + (size_t)c * HID + q * 32 + quad * 8);
    }

    const int slabs = (n + 15) >> 4;
    for (int slab = blockIdx.x; slab < slabs; slab += gridDim.x) {
        const int r0 = slab * 16;
        const int rr = min(r0 + l15, n - 1);

        short8 A[4];
        if (IN_F32) {
            const float* hf = (const float*)hin;
#pragma unroll
            for (int q = 0; q < 4; ++q) {
                const float4 f0 = *(const float4*)(hf + (size_t)rr * HID + q * 32 + quad * 8);
                const float4 f1 = *(const float4*)(hf + (size_t)rr * HID + q * 32 + quad * 8 + 4);
                short8 a;
                a[0] = (short)f32_to_bf16(f0.x); a[1] = (short)f32_to_bf16(f0.y);
                a[2] = (short)f32_to_bf16(f0.z); a[3] = (short)f32_to_bf16(f0.w);
                a[4] = (short)f32_to_bf16(f1.x); a[5] = (short)f32_to_bf16(f1.y);
                a[6] = (short)f32_to_bf16(f1.z); a[7] = (short)f32_to_bf16(f1.w);
                A[q] = a;
            }
        } else {
            const unsigned short* hb = (const unsigned short*)hin;
#pragma unroll
            for (int q = 0; q < 4; ++q)
                A[q] = *(const short8*)(hb + (size_t)rr * HID + q * 32 + quad * 8);
        }

        f32x4 acc[CPW];
#pragma unroll
        for (int t = 0; t < CPW; ++t) acc[t] = (f32x4){0.f, 0.f, 0.f, 0.f};
#pragma unroll
        for (int q = 0; q < 4; ++q)
#pragma unroll
            for (int t = 0; t < CPW; ++t)
                acc[t] = __builtin_amdgcn_mfma_f32_16x16x32_bf16(A[q], B[t][q], acc[t], 0, 0, 0);

        // epilogue: C/D layout col=l15, row=quad*4+i
#pragma unroll
        for (int t = 0; t < CPW; ++t) {
            const int c0  = (wv * CPW + t) * 16;
            const int col = c0 + l15;
            if (c0 < DOUT) {
#pragma unroll
                for (int i = 0; i < 4; ++i) {
                    const int row = r0 + quad * 4 + i;
                    if (row < n) p[(size_t)row * DOUT + col] = f32_to_bf16(acc[t][i]);
                }
            } else {
                const float bv = bias[col - DOUT];
#pragma unroll
                for (int i = 0; i < 4; ++i) {
                    const int row = r0 + quad * 4 + i;
                    if (row < n) {
                        const float v = acc[t][i] + bv;
                        if (R_BF16)
                            ((unsigned short*)r)[(size_t)row * DOUT + (col - DOUT)] = f32_to_bf16(v);
                        else
                            ((float*)r)[(size_t)row * DOUT + (col - DOUT)] = v;
                    }
                }
            }
        }
    }
}

// ---- Post-aggregation: out = act( mean(p_bf16[nbrs]) + r ) ----------------
// One wave per dst node; predicated x8 unroll (8 gathers in flight).
// R_BF16: r is bf16; OUTBF16: write h as packed bf16.

template <int DOUT, bool RELU, bool OUTBF16, bool R_BF16>
__global__ __launch_bounds__(256) void sage_post_aggregate(
    const unsigned short* __restrict__ p, const void* __restrict__ r,
    const int* __restrict__ offs, const int* __restrict__ esrc,
    void* __restrict__ out, int n)
{
    const int wid  = threadIdx.x >> 6;
    const int lane = threadIdx.x & 63;
    const int node = blockIdx.x * 4 + wid;
    if (node >= n) return;
    const int beg = offs[node];
    const int end = offs[node + 1];
    const float inv = 1.0f / fmaxf((float)(end - beg), 1.0f);

    if constexpr (DOUT == 128) {
        float ax[8], ay[8];
#pragma unroll
        for (int j = 0; j < 8; ++j) { ax[j] = 0.f; ay[j] = 0.f; }
        for (int e = beg; e < end; e += 8) {
#pragma unroll
            for (int j = 0; j < 8; ++j) {
                const int idx = e + j;
                const int ee  = min(idx, end - 1);
                const float w = (idx < end) ? 1.0f : 0.0f;
                const int s   = esrc[ee];
                const unsigned int v = *(const unsigned int*)(&p[(size_t)s * DOUT + lane * 2]);
                ax[j] = fmaf(w, bf16_hi_to_f32(v & 0xffffu), ax[j]);
                ay[j] = fmaf(w, bf16_hi_to_f32(v >> 16), ay[j]);
            }
        }
        float sx = ((ax[0] + ax[1]) + (ax[2] + ax[3])) + ((ax[4] + ax[5]) + (ax[6] + ax[7]));
        float sy = ((ay[0] + ay[1]) + (ay[2] + ay[3])) + ((ay[4] + ay[5]) + (ay[6] + ay[7]));
        float rx, ry;
        if (R_BF16) {
            const unsigned int rv = ((const unsigned int*)r)[(size_t)node * (DOUT / 2) + lane];
            rx = bf16_hi_to_f32(rv & 0xffffu);
            ry = bf16_hi_to_f32(rv >> 16);
        } else {
            const float2 rv = *((const float2*)((const float*)r + (size_t)node * DOUT) + lane);
            rx = rv.x; ry = rv.y;
        }
        float ox = sx * inv + rx;
        float oy = sy * inv + ry;
        if (RELU) { ox = fmaxf(ox, 0.f); oy = fmaxf(oy, 0.f); }
        if (OUTBF16) {
            const unsigned int pk = ((unsigned int)f32_to_bf16(oy) << 16) | (unsigned int)f32_to_bf16(ox);
            ((unsigned int*)out)[(size_t)node * (DOUT / 2) + lane] = pk;
        } else {
            float2 o; o.x = ox; o.y = oy;
            *((float2*)((float*)out + (size_t)node * DOUT) + lane) = o;
        }
    } else {
        float a[8];
#pragma unroll
        for (int j = 0; j < 8; ++j) a[j] = 0.f;
        for (int e = beg; e < end; e += 8) {
#pragma unroll
            for (int j = 0; j < 8; ++j) {
                const int idx = e + j;
                const int ee  = min(idx, end - 1);
                const float w = (idx < end) ? 1.0f : 0.0f;
                const int s   = esrc[ee];
                const unsigned short u = p[(size_t)s * DOUT + lane];
                a[j] = fmaf(w, bf16_hi_to_f32((unsigned int)u), a[j]);
            }
        }
        float sa = ((a[0] + a[1]) + (a[2] + a[3])) + ((a[4] + a[5]) + (a[6] + a[7]));
        float rv;
        if (R_BF16) {
            const unsigned short u = ((const unsigned short*)r)[(size_t)node * DOUT + lane];
            rv = bf16_hi_to_f32((unsigned int)u);
        } else {
            rv = ((const float*)r)[(size_t)node * DOUT + lane];
        }
        float o = sa * inv + rv;
        if (RELU) o = fmaxf(o, 0.f);
        ((float*)out)[(size_t)node * DOUT + lane] = o;
    }
}

// ---------------------------------------------------------------------------

static inline size_t align_up(size_t v, size_t a) { return (v + a - 1) & ~(a - 1); }

extern "C" void kernel_launch(void* const* d_in, const int* in_sizes, int n_in,
                              void* d_out, int out_size, void* d_ws, size_t ws_size,
                              hipStream_t stream)
{
    const float* x   = (const float*)d_in[0];
    const int*   ei  = (const int*)d_in[1];      // int32! (harness converts int64)
    const float* wl0 = (const float*)d_in[2];
    const float* b0  = (const float*)d_in[3];
    const float* wr0 = (const float*)d_in[4];
    const float* wl1 = (const float*)d_in[5];
    const float* b1  = (const float*)d_in[6];
    const float* wr1 = (const float*)d_in[7];
    const float* wl2 = (const float*)d_in[8];
    const float* b2  = (const float*)d_in[9];
    const float* wr2 = (const float*)d_in[10];
    float*       out = (float*)d_out;

    const int N = in_sizes[0] / HID;   // 50000
    const int E = in_sizes[1] / 2;     // 800000
    const int* src = ei;
    const int* dst = ei + E;

    // Workspace carve-up (~42 MB)
    char*  ws  = (char*)d_ws;
    size_t off = 0;
    int* offs     = (int*)(ws + off); off = align_up(off + (size_t)(N + 1) * 4, 256);
    int* cursor   = (int*)(ws + off); off = align_up(off + (size_t)N * 4, 256);
    int* deg      = (int*)(ws + off); off = align_up(off + (size_t)N * 4, 256);
    int* partials = (int*)(ws + off); off = align_up(off + 256 * 4, 256);
    int* esrc     = (int*)(ws + off); off = align_up(off + (size_t)E * 4, 256);
    unsigned short* pbuf = (unsigned short*)(ws + off); off = align_up(off + (size_t)N * HID * 2, 256);
    unsigned short* rb16 = (unsigned short*)(ws + off); off = align_up(off + (size_t)N * HID * 2, 256);
    float* rbf32  = (float*)(ws + off); off = align_up(off + (size_t)N * HID * 4, 256);
    unsigned short* hbf = (unsigned short*)(ws + off); off = align_up(off + (size_t)N * HID * 2, 256);
    unsigned short* wt0 = (unsigned short*)(ws + off); off = align_up(off + (size_t)2 * HID * HID * 2, 256);
    unsigned short* wt1 = (unsigned short*)(ws + off); off = align_up(off + (size_t)2 * HID * HID * 2, 256);
    unsigned short* wt2 = (unsigned short*)(ws + off); off = align_up(off + (size_t)HID * HID * 2, 256);
    (void)ws_size; (void)n_in; (void)out_size;

    const int nScanBlk = (N + SCAN_CHUNK - 1) / SCAN_CHUNK;   // 49

    // --- CSR build (reused by all 3 layers) ---
    zero_i32_kernel<<<(N + 255) / 256, 256, 0, stream>>>(deg, N);
    deg_hist_kernel<<<(E + 255) / 256, 256, 0, stream>>>(dst, deg, E, N);
    block_sum_kernel<<<nScanBlk, 256, 0, stream>>>(deg, partials, N);
    scan_write_kernel<<<nScanBlk, 256, 0, stream>>>(deg, partials, offs, cursor, N, E);
    csr_fill_sliced_kernel<<<NSLICE * FILL_BLOCKS_PER_SLICE, 256, 0, stream>>>(
        src, dst, cursor, esrc, E, N);

    // --- W^T prep (all 3 layers, one launch) ---
    prep_wt_all_kernel<<<(2 * (2 * HID * HID) + 2 * 64 * HID + 255) / 256, 256, 0, stream>>>(
        wl0, wr0, wl1, wr1, wl2, wr2, wt0, wt1, wt2);

    const int aggGrid  = (N + 3) / 4;
    const int gemmGrid = 1024;   // grid-stride over 3125 slabs

    // Layer 0: x (f32) -> p/r(bf16) -> hbf (bf16, ReLU)
    sage_mfma_gemm<128, true, true><<<gemmGrid, 256, 0, stream>>>(x, wt0, b0, pbuf, rb16, N);
    sage_post_aggregate<128, true, true, true><<<aggGrid, 256, 0, stream>>>(pbuf, rb16, offs, esrc, hbf, N);

    // Layer 1: hbf -> p/r(bf16) -> hbf (bf16, ReLU)
    sage_mfma_gemm<128, false, true><<<gemmGrid, 256, 0, stream>>>(hbf, wt1, b1, pbuf, rb16, N);
    sage_post_aggregate<128, true, true, true><<<aggGrid, 256, 0, stream>>>(pbuf, rb16, offs, esrc, hbf, N);

    // Layer 2: hbf -> p(bf16)/r(f32) -> out (f32, no ReLU)
    sage_mfma_gemm<64, false, false><<<gemmGrid, 256, 0, stream>>>(hbf, wt2, b2, pbuf, rbf32, N);
    sage_post_aggregate<64, false, false, false><<<aggGrid, 256, 0, stream>>>(pbuf, rbf32, offs, esrc, out, N);
}